// Round 5
// baseline (384.154 us; speedup 1.0000x reference)
//
#include <hip/hip_runtime.h>

// CTC batch cost (K.ctc_batch_cost semantics), B=512, T=512, C=256 (blank=255), L=64.
//
// R5: widen the streaming engine. 8 waves (512 thr) per batch element:
//   wave 0 (consumer): EXACT log-domain alpha recurrence (absmax 0.0 in R3).
//     Only LDS reads + VALU; __syncthreads is free for it (no vmem in flight).
//   waves 1..7 (producers): each owns rows r = (wid-1) + 7*i (i<5) of every
//     32-row chunk. Rows loaded to REGISTERS (global dwordx4, lead-2 double
//     buffer -> ~64 KB in flight per block, ~32 MB chip-wide: 3x BW*latency),
//     class gather in-register via __shfl (ds_bpermute), blank via
//     readlane(f.w,63); producers compute log(p+eps) and ds_write only the
//     compact 65 floats/step. Raw s_barrier + s_waitcnt lgkmcnt(0) so global
//     prefetch loads are NEVER drained at barriers.
// Protocol: barrier #k (k=0..15) = "chunk k published". Slot k&1. Producer
// writes chunk c+2's slot only after barrier #c+1, which the consumer reaches
// only after fully consuming chunk c -> no WAR race. 16 barriers per wave.

#define NEGF (-1e30f)
#define EPSF (1e-7f)

constexpr int T_  = 512;
constexpr int C_  = 256;
constexpr int L_  = 64;
constexpr int TCH = 32;            // time steps per chunk
constexpr int NCH = T_ / TCH;      // 16 chunks
constexpr int NPW = 7;             // producer waves
constexpr int NRW = 5;             // max rows per producer wave per chunk

__device__ __forceinline__ float lae2(float a, float b) {
    float m = fmaxf(a, b);
    float d = fminf(a, b) - m;              // <= 0
    return m + __logf(1.0f + __expf(d));
}

// lane n gets lane n-1's value; lane 0 gets 0.0f (caller overrides with NEGF).
__device__ __forceinline__ float wave_shr1(float x) {
    int r = __builtin_amdgcn_update_dpp(0, __float_as_int(x),
                                        0x138 /* wave_shr:1 */, 0xF, 0xF, true);
    return __int_as_float(r);
}

__global__ __launch_bounds__(512, 4)   // VGPR cap 128 -> 2 blocks/CU resident
void ctc_kernel(const int* __restrict__ y_true,
                const float* __restrict__ y_pred,
                float* __restrict__ out) {
    __shared__ float lpLs[2][TCH][64];  // log p(label_lane)+eps per step, 16 KB
    __shared__ float lpBs[2][TCH];      // log p(blank)+eps per step

    const int b     = blockIdx.x;
    const int tid   = threadIdx.x;
    const int lane  = tid & 63;
    const int wid   = tid >> 6;         // 0 consumer, 1..7 producers
    const int blank = C_ - 1;

    const float* __restrict__ row = y_pred + (size_t)b * T_ * C_;
    const int q = y_true[b * L_ + lane];          // label class of this lane

    if (wid != 0) {
        // ---------------- producers ----------------
        const int w    = wid - 1;                 // 0..6
        const int srcl = q >> 2;                  // lane holding class q
        const float4* src = (const float4*)row + lane;   // classes 4*lane..4*lane+3

        float4 A[NRW], B[NRW];
        auto loadC = [&](int c, float4* buf) {
#pragma unroll
            for (int i = 0; i < NRW; ++i) {
                const int r = w + NPW * i;        // wave-uniform
                if (r < TCH)
                    buf[i] = src[(size_t)(c * TCH + r) * (C_ / 4)];
            }
        };
        auto produce = [&](int slot, const float4* buf) {
#pragma unroll
            for (int i = 0; i < NRW; ++i) {
                const int r = w + NPW * i;
                if (r < TCH) {
                    const float4 f = buf[i];
                    const float vx = __shfl(f.x, srcl, 64);
                    const float vy = __shfl(f.y, srcl, 64);
                    const float vz = __shfl(f.z, srcl, 64);
                    const float vw = __shfl(f.w, srcl, 64);
                    const float t0 = (q & 2) ? vz : vx;
                    const float t1 = (q & 2) ? vw : vy;
                    const float pe = (q & 1) ? t1 : t0;
                    lpLs[slot][r][lane] = __logf(pe + EPSF);
                    const float pb = __int_as_float(
                        __builtin_amdgcn_readlane(__float_as_int(f.w), 63));
                    const float lb = __logf(pb + EPSF);
                    if (lane == 0) lpBs[slot][r] = lb;
                }
            }
        };

        loadC(0, A); loadC(1, B);
        produce(0, A); loadC(2, A);
        __builtin_amdgcn_s_waitcnt(0xC07F);       // lgkmcnt(0) only
        __builtin_amdgcn_s_barrier();             // barrier #0
        for (int cc = 1; cc + 1 < NCH; cc += 2) { // cc = 1,3,...,13
            produce(1, B);                        // chunk cc (odd -> B, slot 1)
            if (cc + 2 < NCH) loadC(cc + 2, B);
            __builtin_amdgcn_s_waitcnt(0xC07F);
            __builtin_amdgcn_s_barrier();         // barrier #cc
            produce(0, A);                        // chunk cc+1 (even -> A, slot 0)
            if (cc + 3 < NCH) loadC(cc + 3, A);
            __builtin_amdgcn_s_waitcnt(0xC07F);
            __builtin_amdgcn_s_barrier();         // barrier #cc+1
        }
        produce(1, B);                            // chunk 15
        __builtin_amdgcn_s_waitcnt(0xC07F);
        __builtin_amdgcn_s_barrier();             // barrier #15
        return;                                   // 16 barriers total
    }

    // ---------------- consumer (wave 0) ----------------
    const int  qp    = (lane == 0) ? blank : y_true[b * L_ + lane - 1];
    const bool skip1 = (q != blank) && (q != qp);

    float a0 = NEGF, a1 = NEGF, a2 = NEGF;

    auto step = [&](float lp0, float lp1) {
        float pa1 = wave_shr1(a1);                // alpha[2l-1]
        if (lane == 0) pa1 = NEGF;
        const float na0 = lae2(a0, pa1) + lp0;    // state 2l (blank)
        const float c3  = skip1 ? pa1 : NEGF;
        const float m   = fmaxf(fmaxf(a1, a0), c3);
        const float s   = __expf(a1 - m) + __expf(a0 - m) + __expf(c3 - m);
        const float na1 = m + __logf(s) + lp1;    // state 2l+1 (label)
        const float na2 = lae2(a2, a1) + lp0;     // state 128 (final blank)
        a0 = na0; a1 = na1; a2 = na2;
    };
    auto half = [&](int slot, int jbase, bool init) {
        float l1[16], l0[16];
#pragma unroll
        for (int j = 0; j < 16; ++j) {
            l1[j] = lpLs[slot][jbase + j][lane];  // stride-1: free 2-way alias
            l0[j] = lpBs[slot][jbase + j];        // uniform broadcast
        }
        int j0 = 0;
        if (init) {
            a0 = (lane == 0) ? l0[0] : NEGF;      // alpha0[0] = log p(blank)
            a1 = (lane == 0) ? l1[0] : NEGF;      // alpha0[1] = log p(l1)
            a2 = NEGF;
            j0 = 1;
        }
#pragma unroll
        for (int j = 0; j < 16; ++j)
            if (j >= j0) step(l0[j], l1[j]);
    };

    __syncthreads();                              // barrier #0
    half(0, 0, true); half(0, 16, false);         // chunk 0
    for (int c = 1; c < NCH; ++c) {
        __syncthreads();                          // barrier #c
        const int slot = c & 1;
        half(slot, 0, false); half(slot, 16, false);
    }

    if (lane == 63) {
        out[b] = -lae2(a1, a2);                   // -logaddexp(alpha[128], alpha[127])
    }
}

extern "C" void kernel_launch(void* const* d_in, const int* in_sizes, int n_in,
                              void* d_out, int out_size, void* d_ws, size_t ws_size,
                              hipStream_t stream) {
    const int*   y_true = (const int*)d_in[0];
    const float* y_pred = (const float*)d_in[1];
    float*       out    = (float*)d_out;

    const int B = in_sizes[0] / L_;               // 512
    ctc_kernel<<<dim3(B), dim3(512), 0, stream>>>(y_true, y_pred, out);
}